// Round 7
// baseline (184.096 us; speedup 1.0000x reference)
//
#include <hip/hip_runtime.h>
#include <math.h>

// Problem constants
#define BB   16
#define CC   64
#define DIN  192     // C*K
#define DOUT 128
#define NEXP 8
#define NMAT 9       // 8 routed + 1 shared (fallback path only)
#define NTOK 65536   // B*H*W

#define TOKSTRIDE 200   // LDS bf16 token row stride
#define LOGSTRIDE 9

typedef short bf16x8 __attribute__((ext_vector_type(8)));
typedef float f32x4  __attribute__((ext_vector_type(4)));

// ---- workspace layout (bytes) ----
// r6: slab pipeline deleted. Only tokbuf + folded wt + per-token routing info.
#define WS_TOK   0u          // bf16[NTOK][192]            25165824
#define WS_WT    25165824u   // bf16[8][128][192] folded   393216 (+pad)
#define WS_TI    25608192u   // float4[NTOK] g0,g1,e0,e1   1048576
#define WS_TOTAL 26656768u

__device__ __forceinline__ unsigned short f2bf(float f) {
    union { float f; unsigned u; } v; v.f = f;
    unsigned u = v.u;
    u += 0x7fffu + ((u >> 16) & 1u);   // RNE (inputs finite)
    return (unsigned short)(u >> 16);
}
__device__ __forceinline__ float bf2f(unsigned short s) {
    union { unsigned u; float f; } v; v.u = ((unsigned)s) << 16;
    return v.f;
}

// ---------------- K1a: conv + router -> tokbuf + tokinfo (r6) ----------------
// Conv part = r3's best-measured form (closed for micro-opt, ~41us).
// Routing output is per-token (g0,g1,e0,e1) only -- no global bucket append,
// no cnt atomics, no memset node. Folded weights (We+Ws)^T prepared here
// (g0+g1=1 identity absorbs the shared expert exactly).
__global__ __launch_bounds__(256)
void k1a_conv(const float* __restrict__ x,
              const float* __restrict__ conv_w,
              const float* __restrict__ router_w,
              const float* __restrict__ w_experts,
              const float* __restrict__ w_shared,
              unsigned short* __restrict__ tokbuf,
              unsigned short* __restrict__ wt,
              float* __restrict__ tokinfo)
{
    __shared__ __attribute__((aligned(16))) unsigned short tokbf[64 * TOKSTRIDE];
    __shared__ float logits[64 * LOGSTRIDE];

    const int tid = threadIdx.x;
    const int bh  = blockIdx.x;          // 1024 = (b,h)
    const int b   = bh >> 6;
    const int h   = bh & 63;

    for (int idx = tid; idx < 64 * LOGSTRIDE; idx += 256) logits[idx] = 0.f;
    __syncthreads();

    // folded-weight transpose slice: 192 elems/block (1024*192 = 8*128*192)
    // wt[e][n][k] = f2bf(w_experts[e][k][n] + w_shared[k][n])
    {
        int idx = bh * 192 + tid;
        if (tid < 192) {
            int e = idx / 24576, rem = idx - e * 24576;
            int n = rem / DIN,  k  = rem - n * DIN;
            wt[idx] = f2bf(w_experts[(size_t)e * 24576 + k * DOUT + n]
                           + w_shared[k * DOUT + n]);
        }
    }

    const int   h0  = (h > 0)  ? (h - 1) : 0;
    const int   h2  = (h < 63) ? (h + 1) : 63;
    const float mh0 = (h > 0)  ? 1.f : 0.f;
    const float mh2 = (h < 63) ? 1.f : 0.f;

    const int w = tid & 63;
    const int q = __builtin_amdgcn_readfirstlane(tid >> 6); // wave-uniform

    const int   wm  = (w == 0)  ? 0  : (w - 1);
    const int   wp  = (w == 63) ? 63 : (w + 1);
    const float mwm = (w == 0)  ? 0.f : 1.f;
    const float mwp = (w == 63) ? 0.f : 1.f;

    float lacc[8];
    #pragma unroll
    for (int e = 0; e < 8; ++e) lacc[e] = 0.f;

    const float* xb = x + (size_t)b * CC * 4096;

    // wave q owns channels q*16 .. q*16+15 (features q*48 .. q*48+47)
    #pragma unroll 2
    for (int i = 0; i < 16; ++i) {
        const int c = q * 16 + i;
        const float* xc = xb + (size_t)c * 4096;
        const float* r0 = xc + h0 * 64;
        const float* r1 = xc + h  * 64;
        const float* r2 = xc + h2 * 64;
        float x00 = r0[wm], x01 = r0[w], x02 = r0[wp];
        float x10 = r1[wm], x11 = r1[w], x12 = r1[wp];
        float x20 = r2[wm], x21 = r2[w], x22 = r2[wp];
        x00 *= mh0 * mwm; x01 *= mh0; x02 *= mh0 * mwp;
        x10 *= mwm;                    x12 *= mwp;
        x20 *= mh2 * mwm; x21 *= mh2; x22 *= mh2 * mwp;

        #pragma unroll
        for (int j = 0; j < 3; ++j) {
            const int f = 3 * c + j;               // wave-uniform
            const float* w9  = conv_w + f * 9;     // scalar loads (L2-hot)
            const float* rwf = router_w + f * 8;   // scalar loads
            float acc = x00 * w9[0] + x01 * w9[1] + x02 * w9[2]
                      + x10 * w9[3] + x11 * w9[4] + x12 * w9[5]
                      + x20 * w9[6] + x21 * w9[7] + x22 * w9[8];
            tokbf[w * TOKSTRIDE + f] = f2bf(acc);
            #pragma unroll
            for (int e = 0; e < 8; ++e) lacc[e] += acc * rwf[e];
        }
    }

    #pragma unroll
    for (int e = 0; e < 8; ++e)
        atomicAdd(&logits[w * LOGSTRIDE + e], lacc[e]);  // 4 threads/(w,e)
    __syncthreads();

    // ---- per-token routing info: top-2, gates ----
    if (tid < 64) {
        float l[8];
        #pragma unroll
        for (int e = 0; e < 8; ++e) l[e] = logits[tid * LOGSTRIDE + e];
        // fp32 exact top-2; strict > keeps lowest index on ties (lax.top_k)
        int e0 = 0; float l0 = l[0];
        #pragma unroll
        for (int e = 1; e < 8; ++e) if (l[e] > l0) { l0 = l[e]; e0 = e; }
        int e1 = -1; float l1 = -INFINITY;
        #pragma unroll
        for (int e = 0; e < 8; ++e) {
            if (e == e0) continue;
            if (l[e] > l1) { l1 = l[e]; e1 = e; }
        }
        float g0 = 1.f / (1.f + expf(l1 - l0));   // softmax Z cancels in renorm
        float4 v;
        v.x = g0; v.y = 1.f - g0;
        v.z = __int_as_float(e0); v.w = __int_as_float(e1);
        *(float4*)(tokinfo + (size_t)(bh * 64 + tid) * 4) = v;
    }

    // tokens LDS -> global (bf16x8 chunks; 64 rows x 24 chunks)
    for (int idx = tid; idx < 1536; idx += 256) {
        int row = idx / 24, seg = idx - row * 24;
        *(bf16x8*)(tokbuf + (size_t)(bh * 64 + row) * 192 + seg * 8) =
            *(const bf16x8*)(tokbf + row * TOKSTRIDE + seg * 8);
    }
}

// ---------------- K2: fused bucketed GEMM + combine + store (r7) -------------
// One block per 64-token (b,h) row. Local expert buckets (16-row tiles,
// <=15 tiles). Wave w owns out-cols [w*32, w*32+32): processes ALL tiles
// sequentially for its columns -> out_lds read-modify-write needs NO atomics
// for REAL entries (each (token,col) touched by exactly one wave, in program
// order). r7 BUGFIX: pad entries all carry token 0 / gate 0 -- in r6 their
// +=0 RMW could collide same-address with the real token 0 in the same
// ds_read/ds_write pair and LOSE its update (absmax 0.80). Pads are now
// skipped via the gate!=0 predicate, restoring per-lane address uniqueness.
__global__ __launch_bounds__(256)
void k2_moe(const unsigned short* __restrict__ tokbuf,
            const unsigned short* __restrict__ wt,
            const float* __restrict__ b_experts,
            const float* __restrict__ b_shared,
            const float* __restrict__ tokinfo,
            float* __restrict__ out)
{
    __shared__ __attribute__((aligned(16))) unsigned short tokbf[64 * TOKSTRIDE];
    __shared__ float out_lds[64 * 129];            // 33 KB, fp32 accum
    __shared__ float bsum[NEXP * DOUT];            // b_e + b_s
    __shared__ int   rowtok[256];
    __shared__ float rowgate[256];
    __shared__ int   lcnt[8], lstart[8];
    __shared__ int   tilexp[16], tilebase[16];
    __shared__ int   ntiles_s;

    const int tid = threadIdx.x;
    const int bh  = blockIdx.x;            // 1024
    const int b   = bh >> 6;
    const int h   = bh & 63;
    const size_t t0 = (size_t)bh * 64;

    // stage this block's 64 token rows (coalesced)
    for (int idx = tid; idx < 1536; idx += 256) {
        int row = idx / 24, seg = idx - row * 24;
        *(bf16x8*)&tokbf[row * TOKSTRIDE + seg * 8] =
            *(const bf16x8*)(tokbuf + (t0 + row) * 192 + seg * 8);
    }
    for (int idx = tid; idx < NEXP * DOUT; idx += 256)
        bsum[idx] = b_experts[idx] + b_shared[idx & 127];
    if (tid < 8) lcnt[tid] = 0;
    for (int idx = tid; idx < 64 * 129; idx += 256) out_lds[idx] = 0.f;
    __syncthreads();

    // routing info + local ranks
    int e0 = 0, e1 = 0, r0 = 0, r1 = 0;
    float g0 = 0.f, g1 = 0.f;
    if (tid < 64) {
        float4 ti = *(const float4*)(tokinfo + (t0 + tid) * 4);
        g0 = ti.x; g1 = ti.y;
        e0 = __float_as_int(ti.z); e1 = __float_as_int(ti.w);
        r0 = atomicAdd(&lcnt[e0], 1);
        r1 = atomicAdd(&lcnt[e1], 1);
    }
    __syncthreads();
    if (tid == 0) {
        int start = 0, tb = 0;
        for (int e = 0; e < 8; ++e) {
            lstart[e] = start;
            int tl = (lcnt[e] + 15) >> 4;
            for (int j = 0; j < tl; ++j) {
                tilexp[tb + j] = e; tilebase[tb + j] = start + (j << 4);
            }
            start += tl << 4; tb += tl;
        }
        ntiles_s = tb;
    }
    __syncthreads();
    if (tid < 64) {
        int p0 = lstart[e0] + r0, p1 = lstart[e1] + r1;
        rowtok[p0] = tid; rowgate[p0] = g0;
        rowtok[p1] = tid; rowgate[p1] = g1;
    }
    if (tid < 8) {                       // pad tails: token 0, gate 0 (skipped)
        int e = tid, tl = (lcnt[e] + 15) >> 4;
        for (int j = lcnt[e]; j < (tl << 4); ++j) {
            rowtok[lstart[e] + j] = 0; rowgate[lstart[e] + j] = 0.f;
        }
    }
    __syncthreads();

    // GEMM: wave owns 2 n-blocks (32 out cols); sequential tiles -> safe RMW
    const int wave = tid >> 6, lane = tid & 63;
    const int m16  = lane & 15, quad = lane >> 4;
    const int nt   = ntiles_s;
    for (int ti = 0; ti < nt; ++ti) {
        int e = tilexp[ti], base = tilebase[ti];
        int tA = rowtok[base + m16];
        bf16x8 a[6];
        #pragma unroll
        for (int ks = 0; ks < 6; ++ks)
            a[ks] = *(const bf16x8*)&tokbf[tA * TOKSTRIDE + ks * 32 + quad * 8];
        int st[4]; float sg[4];
        #pragma unroll
        for (int i = 0; i < 4; ++i) {
            int r = base + quad * 4 + i;
            st[i] = rowtok[r]; sg[i] = rowgate[r];
        }
        const unsigned short* we = wt + (size_t)e * DOUT * DIN;
        #pragma unroll
        for (int nb2 = 0; nb2 < 2; ++nb2) {
            int o = (wave * 2 + nb2) * 16 + m16;
            const unsigned short* wp = we + (size_t)o * DIN + quad * 8;
            f32x4 acc = {0.f, 0.f, 0.f, 0.f};
            #pragma unroll
            for (int ks = 0; ks < 6; ++ks) {
                bf16x8 bfr = *(const bf16x8*)(wp + ks * 32);
                acc = __builtin_amdgcn_mfma_f32_16x16x32_bf16(a[ks], bfr, acc, 0, 0, 0);
            }
            float be = bsum[e * DOUT + o];
            #pragma unroll
            for (int i = 0; i < 4; ++i)
                if (sg[i] != 0.f)              // r7: skip pads (see header)
                    out_lds[st[i] * 129 + o] += sg[i] * (acc[i] + be);
        }
    }
    __syncthreads();

    // transposed coalesced store: out[b][o][h][w]
    float* outp = out + ((size_t)b * DOUT) * 4096 + h * 64;
    for (int idx = tid; idx < 64 * DOUT; idx += 256) {
        int w = idx & 63, o = idx >> 6;
        outp[(size_t)o * 4096 + w] = out_lds[w * 129 + o];
    }
}

// ================== fallback (round-3 fused path, needs only 442 KB ws) ======
#define OUTSTRIDE 129
#define MAXROWS 320
#define MAXTILES 20

__global__ __launch_bounds__(256)
void moe_conv2d_mfma(const float* __restrict__ x,
                     const float* __restrict__ conv_w,
                     const float* __restrict__ router_w,
                     const unsigned short* __restrict__ wt,
                     const float* __restrict__ b_experts,
                     const float* __restrict__ b_shared,
                     float* __restrict__ out)
{
    __shared__ __attribute__((aligned(16))) unsigned short tokbf[64 * TOKSTRIDE];
    __shared__ float out_lds[64 * OUTSTRIDE];
    __shared__ float rw[DIN * NEXP];
    __shared__ float logits[64 * LOGSTRIDE];
    __shared__ float sg0[64], sg1[64];
    __shared__ int   se0[64], se1[64];
    __shared__ int   rowtok[MAXROWS];
    __shared__ float rowgate[MAXROWS];
    __shared__ int   cbuf[NMAT];
    __shared__ int   tilexp[MAXTILES], tilebase[MAXTILES];
    __shared__ int   ntiles_s;

    const int tid = threadIdx.x;
    const int bh  = blockIdx.x;
    const int b   = bh >> 6;
    const int h   = bh & 63;

    for (int idx = tid; idx < DIN * NEXP; idx += 256) rw[idx] = router_w[idx];
    for (int idx = tid; idx < 64 * LOGSTRIDE; idx += 256) logits[idx] = 0.f;
    __syncthreads();
    {
        const int w  = tid & 63;
        const int fq = tid >> 6;
        float lacc[8];
        #pragma unroll
        for (int e = 0; e < 8; ++e) lacc[e] = 0.f;
        for (int i = 0; i < 48; ++i) {
            int f = i * 4 + fq;
            int c = f / 3;
            const float* wp    = conv_w + f * 9;
            const float* xbase = x + ((size_t)(b * 64 + c) * 64) * 64;
            float acc = 0.f;
            #pragma unroll
            for (int kh = 0; kh < 3; ++kh) {
                int hh = h + kh - 1;
                if (hh < 0 || hh > 63) continue;
                const float* xrow = xbase + hh * 64;
                #pragma unroll
                for (int kw = 0; kw < 3; ++kw) {
                    int ww = w + kw - 1;
                    if (ww < 0 || ww > 63) continue;
                    acc += xrow[ww] * wp[kh * 3 + kw];
                }
            }
            tokbf[w * TOKSTRIDE + f] = f2bf(acc);
            const float* rwf = rw + f * 8;
            #pragma unroll
            for (int e = 0; e < 8; ++e) lacc[e] += acc * rwf[e];
        }
        #pragma unroll
        for (int e = 0; e < 8; ++e)
            atomicAdd(&logits[w * LOGSTRIDE + e], lacc[e]);
    }
    __syncthreads();
    if (tid < 64) {
        int w = tid;
        float l[8];
        #pragma unroll
        for (int e = 0; e < 8; ++e) l[e] = logits[w * LOGSTRIDE + e];
        int e0 = 0; float l0 = l[0];
        #pragma unroll
        for (int e = 1; e < 8; ++e) if (l[e] > l0) { l0 = l[e]; e0 = e; }
        int e1 = -1; float l1 = -INFINITY;
        #pragma unroll
        for (int e = 0; e < 8; ++e) {
            if (e == e0) continue;
            if (l[e] > l1) { l1 = l[e]; e1 = e; }
        }
        float g0 = 1.f / (1.f + expf(l1 - l0));
        sg0[w] = g0; sg1[w] = 1.f - g0;
        se0[w] = e0; se1[w] = e1;
    }
    __syncthreads();
    for (int idx = tid; idx < 64 * DOUT; idx += 256) {
        int t = idx >> 7, o = idx & 127;
        out_lds[t * OUTSTRIDE + o] = b_shared[o]
            + sg0[t] * b_experts[se0[t] * DOUT + o]
            + sg1[t] * b_experts[se1[t] * DOUT + o];
    }
    if (tid < 8) {
        int c = 0;
        for (int t = 0; t < 64; ++t) c += (se0[t] == tid) + (se1[t] == tid);
        cbuf[tid] = c;
    } else if (tid == 8) cbuf[8] = 64;
    __syncthreads();
    if (tid < NMAT) {
        int e = tid;
        int start = 0, tb = 0;
        for (int e2 = 0; e2 < e; ++e2) {
            int ce = cbuf[e2];
            int tl = (ce + 15) >> 4;
            start += tl << 4; tb += tl;
        }
        int ce = cbuf[e];
        int tl = (ce + 15) >> 4;
        for (int j = 0; j < tl; ++j) { tilexp[tb + j] = e; tilebase[tb + j] = start + (j << 4); }
        if (e == 8) ntiles_s = tb + tl;
        int j = 0;
        if (e < 8) {
            for (int t = 0; t < 64; ++t) {
                if (se0[t] == e) { rowtok[start + j] = t; rowgate[start + j] = sg0[t]; ++j; }
                if (se1[t] == e) { rowtok[start + j] = t; rowgate[start + j] = sg1[t]; ++j; }
            }
        } else {
            for (int t = 0; t < 64; ++t) { rowtok[start + j] = t; rowgate[start + j] = 1.f; ++j; }
        }
        for (; j < (tl << 4); ++j) { rowtok[start + j] = 0; rowgate[start + j] = 0.f; }
    }
    __syncthreads();
    {
        const int wave = tid >> 6;
        const int lane = tid & 63;
        const int m16  = lane & 15;
        const int quad = lane >> 4;
        const int nt   = ntiles_s;
        for (int ti = wave; ti < nt; ti += 4) {
            int e    = tilexp[ti];
            int base = tilebase[ti];
            int tA = rowtok[base + m16];
            bf16x8 a[6];
            #pragma unroll
            for (int ks = 0; ks < 6; ++ks)
                a[ks] = *(const bf16x8*)(tokbf + tA * TOKSTRIDE + ks * 32 + quad * 8);
            int st[4]; float sgt[4];
            #pragma unroll
            for (int i2 = 0; i2 < 4; ++i2) {
                int r = base + quad * 4 + i2;
                st[i2] = rowtok[r]; sgt[i2] = rowgate[r];
            }
            const unsigned short* we = wt + (size_t)e * DOUT * DIN;
            for (int n = 0; n < 8; ++n) {
                const unsigned short* wp = we + (size_t)(n * 16 + m16) * DIN + quad * 8;
                f32x4 acc = {0.f, 0.f, 0.f, 0.f};
                #pragma unroll
                for (int ks = 0; ks < 6; ++ks) {
                    bf16x8 bfr2 = *(const bf16x8*)(wp + ks * 32);
                    acc = __builtin_amdgcn_mfma_f32_16x16x32_bf16(a[ks], bfr2, acc, 0, 0, 0);
                }
                int ncol = n * 16 + m16;
                #pragma unroll
                for (int i2 = 0; i2 < 4; ++i2)
                    atomicAdd(&out_lds[st[i2] * OUTSTRIDE + ncol], sgt[i2] * acc[i2]);
            }
        }
    }
    __syncthreads();
    {
        float* outp = out + (((size_t)b * DOUT) * 64 + h) * 64;
        for (int idx = tid; idx < 64 * DOUT; idx += 256) {
            int w = idx & 63, o = idx >> 6;
            outp[(size_t)o * 4096 + w] = out_lds[w * OUTSTRIDE + o];
        }
    }
}

__global__ __launch_bounds__(256)
void prep_weights_only(const float* __restrict__ w_experts,
                       const float* __restrict__ w_shared,
                       unsigned short* __restrict__ wt)
{
    int e = blockIdx.x;
    const float* src = (e < 8) ? (w_experts + (size_t)e * DIN * DOUT) : w_shared;
    unsigned short* dst = wt + (size_t)e * DOUT * DIN;
    for (int idx = threadIdx.x; idx < DOUT * DIN; idx += 256) {
        int n = idx / DIN, k = idx - n * DIN;
        dst[idx] = f2bf(src[k * DOUT + n]);
    }
}

// =============================================================================
extern "C" void kernel_launch(void* const* d_in, const int* in_sizes, int n_in,
                              void* d_out, int out_size, void* d_ws, size_t ws_size,
                              hipStream_t stream)
{
    const float* x         = (const float*)d_in[0];
    const float* conv_w    = (const float*)d_in[1];
    const float* router_w  = (const float*)d_in[2];
    const float* w_experts = (const float*)d_in[3];
    const float* b_experts = (const float*)d_in[4];
    const float* w_shared  = (const float*)d_in[5];
    const float* b_shared  = (const float*)d_in[6];
    float* out = (float*)d_out;
    char* ws = (char*)d_ws;

    if (ws_size >= WS_TOTAL) {
        unsigned short* tokbuf  = (unsigned short*)(ws + WS_TOK);
        unsigned short* wt      = (unsigned short*)(ws + WS_WT);
        float*          tokinfo = (float*)(ws + WS_TI);

        k1a_conv<<<dim3(1024), dim3(256), 0, stream>>>(
            x, conv_w, router_w, w_experts, w_shared, tokbuf, wt, tokinfo);
        k2_moe<<<dim3(1024), dim3(256), 0, stream>>>(
            tokbuf, wt, b_experts, b_shared, tokinfo, out);
    } else {
        // fallback: round-3 fused path (needs only 442 KB ws)
        unsigned short* wt = (unsigned short*)ws;
        prep_weights_only<<<dim3(NMAT), dim3(256), 0, stream>>>(w_experts, w_shared, wt);
        moe_conv2d_mfma<<<dim3(1024), dim3(256), 0, stream>>>(
            x, conv_w, router_w, wt, b_experts, b_shared, out);
    }
}